// Round 8
// baseline (7319.594 us; speedup 1.0000x reference)
//
#include <hip/hip_runtime.h>
#include <hip/hip_bf16.h>
#include <hip/hip_fp16.h>
#include <type_traits>

#define S_LEN 1024
#define BATCH 16
#define HID   384
#define DIN   768

// ---------------- LSTM scan configuration (R0 structure) ----------------
// 32 groups = (dir, batch); 8 members per group; UPB units per member.
// R6: f16 weights streamed from global. R7/R8: the 24 weight loads are issued
// into REGISTERS BEFORE the poll (they don't depend on h) -> their L2
// latency/BW hides under the exchange RTT instead of sitting on the
// post-barrier critical path. (R6 measured: halving weight bytes gave only
// -4% -> the exchange RTT is the floor; weight latency was additive.)
// R8 fix: pin wpre component-wise ("+v" on scalar floats -- the float4 form
// hit "tied indirect register inputs" in the backend).
#define GRP 8
#define UPB 48
#define NTHR 384

__device__ __forceinline__ float sigf(float x)     { return 1.f/(1.f + __expf(-x)); }
__device__ __forceinline__ float tanhfast(float x) { return 1.f - 2.f/(__expf(2.f*x) + 1.f); }

__device__ __forceinline__ __half2 unpackh2(float f) {
    return __builtin_bit_cast(__half2, f);
}

typedef __attribute__((ext_vector_type(8))) _Float16 f16x8;
typedef __attribute__((ext_vector_type(4))) float f32x4;

// ---------------- zero init: packed h-exchange {tag,val} buffer ----------------
// 32 groups x 2 slots x 384 units x 8B = 196,608 B. Must be zeroed every launch
// (harness poisons d_ws with 0xAA -> tags would read as huge -> stale accept).
__global__ void zero_kernel(unsigned long long* hx)
{
    int i = blockIdx.x * blockDim.x + threadIdx.x;
    if (i < 32*2*HID) hx[i] = 0ull;
}

// ---------------- Whh f32 -> f16 pre-convert (both directions) ----------------
__global__ void prep16(const float* __restrict__ wf, const float* __restrict__ wb,
                       __half* __restrict__ o)
{
    int i = blockIdx.x * 256 + threadIdx.x;   // 0..147455 float4s per matrix
    if (i < 147456) {
        const float4 a = ((const float4*)wf)[i];
        const float4 b = ((const float4*)wb)[i];
        __half2* of = (__half2*)o;
        of[2*i]   = __halves2half2(__float2half(a.x), __float2half(a.y));
        of[2*i+1] = __halves2half2(__float2half(a.z), __float2half(a.w));
        __half2* ob = (__half2*)(o + 589824);
        ob[2*i]   = __halves2half2(__float2half(b.x), __float2half(b.y));
        ob[2*i+1] = __halves2half2(__float2half(b.z), __float2half(b.w));
    }
}

// ---------------- head fusion prep: Wc = w1 @ fc1_W ; bc = w1 @ fc1_b + b1 ----
// Exact algebra: h2 = seq@fc1W^T + fc1b ; y1 = relu(h2@w1^T + b1)
//             -> y1 = relu(seq @ Wc^T + bc), Wc[n][k] = sum_j w1[n][j]*fc1W[j][k].
// grid 256 (one n per block), 256 threads (3 k-columns each, coalesced over k).
__global__ __launch_bounds__(256) void prep_wc(
    const float* __restrict__ fc1W,  // [384][768]
    const float* __restrict__ fc1b,  // [384]
    const float* __restrict__ w1,    // [256][384]
    const float* __restrict__ b1,    // [256]
    float* __restrict__ Wc,          // [256][768]
    float* __restrict__ bc)          // [256]
{
    __shared__ float wr[384];
    const int n = blockIdx.x;
    const int tid = threadIdx.x;
    if (tid < 192) {
        const float2 v = *(const float2*)(w1 + (size_t)n * 384 + tid * 2);
        wr[tid*2] = v.x; wr[tid*2+1] = v.y;
    }
    __syncthreads();
    float s0 = 0.f, s1 = 0.f, s2 = 0.f;
    for (int j = 0; j < 384; j++) {
        const float w = wr[j];
        const float* fr = fc1W + (size_t)j * 768;
        s0 += w * fr[tid]; s1 += w * fr[tid + 256]; s2 += w * fr[tid + 512];
    }
    Wc[(size_t)n*768 + tid]       = s0;
    Wc[(size_t)n*768 + tid + 256] = s1;
    Wc[(size_t)n*768 + tid + 512] = s2;
    if (tid == 0) {
        float s = b1[n];
        for (int j = 0; j < 384; j++) s += wr[j] * fc1b[j];
        bc[n] = s;
    }
}

// ---------------- MFMA f16 GEMM: C = act(A(f32) @ W(f32)^T + bias) ----------------
// M mult 128, N mult 128, K mult 64. BM=BN=128, BK=64, 256 threads = 4 waves 2x2,
// wave-tile 64x64, acc[4][4] f32x4. LDS tiles f16 [128][128B], XOR swizzle
// byte ^= (row&7)<<4 on write and read -> conflict-free. Verified in R6 (absmax
// unchanged). Fragment layouts m89/m93: A lane row=fr, k=fq*8+e; C row=fq*4+j, col=fr.
template<int RELU, typename OT>
__global__ __launch_bounds__(256) void gemm_f16(
    const float* __restrict__ A, int ldA,
    const float* __restrict__ W,            // [N][K] f32
    const float* __restrict__ bias,
    OT* __restrict__ C, int ldC,
    int K)
{
    __shared__ char Al[128 * 128];
    __shared__ char Bl[128 * 128];
    const int tid  = threadIdx.x;
    const int m0   = blockIdx.x * 128;
    const int n0   = blockIdx.y * 128;
    const int wid  = tid >> 6, lane = tid & 63;
    const int wm   = (wid >> 1) * 64, wn = (wid & 1) * 64;
    const int fr   = lane & 15, fq = lane >> 4;

    f32x4 acc[4][4] = {};

    const int srow = tid >> 1;            // 0..127
    const int sseg = (tid & 1) * 32;      // element offset 0 or 32

    for (int k0 = 0; k0 < K; k0 += 64) {
        {
            const float* ap = A + (size_t)(m0 + srow) * ldA + k0 + sseg;
            const float* wp = W + (size_t)(n0 + srow) * K   + k0 + sseg;
            _Float16 ta[32], tw[32];
            #pragma unroll
            for (int q = 0; q < 8; q++) {
                const float4 va = *(const float4*)(ap + q * 4);
                const float4 vw = *(const float4*)(wp + q * 4);
                ta[4*q+0] = (_Float16)va.x; ta[4*q+1] = (_Float16)va.y;
                ta[4*q+2] = (_Float16)va.z; ta[4*q+3] = (_Float16)va.w;
                tw[4*q+0] = (_Float16)vw.x; tw[4*q+1] = (_Float16)vw.y;
                tw[4*q+2] = (_Float16)vw.z; tw[4*q+3] = (_Float16)vw.w;
            }
            const int xr = (srow & 7) << 4;
            #pragma unroll
            for (int c = 0; c < 4; c++) {
                const int col = (sseg * 2 + c * 16) ^ xr;   // byte col
                *(f16x8*)(Al + srow * 128 + col) = *(f16x8*)&ta[c * 8];
                *(f16x8*)(Bl + srow * 128 + col) = *(f16x8*)&tw[c * 8];
            }
        }
        __syncthreads();

        #pragma unroll
        for (int kc = 0; kc < 2; kc++) {
            f16x8 af[4], bf[4];
            #pragma unroll
            for (int mt = 0; mt < 4; mt++) {
                const int r = wm + mt * 16 + fr;
                af[mt] = *(const f16x8*)(Al + r * 128 + ((kc * 64 + fq * 16) ^ ((r & 7) << 4)));
            }
            #pragma unroll
            for (int nt = 0; nt < 4; nt++) {
                const int r = wn + nt * 16 + fr;
                bf[nt] = *(const f16x8*)(Bl + r * 128 + ((kc * 64 + fq * 16) ^ ((r & 7) << 4)));
            }
            #pragma unroll
            for (int mt = 0; mt < 4; mt++)
                #pragma unroll
                for (int nt = 0; nt < 4; nt++)
                    acc[mt][nt] = __builtin_amdgcn_mfma_f32_16x16x32_f16(
                        af[mt], bf[nt], acc[mt][nt], 0, 0, 0);
        }
        __syncthreads();
    }

    #pragma unroll
    for (int mt = 0; mt < 4; mt++) {
        #pragma unroll
        for (int nt = 0; nt < 4; nt++) {
            const int n = n0 + wn + nt * 16 + fr;
            const float bv = bias[n];
            #pragma unroll
            for (int j = 0; j < 4; j++) {
                const int m = m0 + wm + mt * 16 + fq * 4 + j;
                float v = acc[mt][nt][j] + bv;
                if (RELU) v = fmaxf(v, 0.f);
                if constexpr (std::is_same_v<OT, __hip_bfloat16>)
                    C[(size_t)m * ldC + n] = __float2bfloat16(v);
                else
                    C[(size_t)m * ldC + n] = v;
            }
        }
    }
}

// ---------------- generic fp32 GEMM (kept for small/odd-N tails) ----------------
template<int RELU, typename OT>
__global__ __launch_bounds__(256) void gemm_nt(
    const float* __restrict__ A, int ldA,
    const float* __restrict__ W,
    const float* __restrict__ bias,
    OT* __restrict__ C, int ldC,
    int M, int N, int K)
{
    __shared__ float As[16][132];
    __shared__ float Ws[16][68];
    const int tid = threadIdx.x;
    const int m0 = blockIdx.x * 128;
    const int n0 = blockIdx.y * 64;
    const int tm = (tid & 15) * 8;
    const int tn = (tid >> 4) * 4;

    float acc[8][4];
    #pragma unroll
    for (int i = 0; i < 8; i++)
        #pragma unroll
        for (int j = 0; j < 4; j++) acc[i][j] = 0.f;

    const int lrow = tid >> 2;          // 0..63
    const int lk   = (tid & 3) * 4;     // 0,4,8,12

    for (int k0 = 0; k0 < K; k0 += 16) {
        #pragma unroll
        for (int p = 0; p < 2; p++) {
            const int r = lrow + p * 64;
            const float4 av = *(const float4*)(A + (size_t)(m0 + r) * ldA + k0 + lk);
            As[lk+0][r] = av.x; As[lk+1][r] = av.y; As[lk+2][r] = av.z; As[lk+3][r] = av.w;
        }
        {
            float4 wv = make_float4(0.f, 0.f, 0.f, 0.f);
            if (n0 + lrow < N) wv = *(const float4*)(W + (size_t)(n0 + lrow) * K + k0 + lk);
            Ws[lk+0][lrow] = wv.x; Ws[lk+1][lrow] = wv.y; Ws[lk+2][lrow] = wv.z; Ws[lk+3][lrow] = wv.w;
        }
        __syncthreads();
        #pragma unroll
        for (int k = 0; k < 16; k++) {
            const float4 a0 = *(const float4*)&As[k][tm];
            const float4 a1 = *(const float4*)&As[k][tm + 4];
            const float4 bv = *(const float4*)&Ws[k][tn];
            const float am[8] = {a0.x, a0.y, a0.z, a0.w, a1.x, a1.y, a1.z, a1.w};
            const float bb[4] = {bv.x, bv.y, bv.z, bv.w};
            #pragma unroll
            for (int i = 0; i < 8; i++)
                #pragma unroll
                for (int j = 0; j < 4; j++) acc[i][j] += am[i] * bb[j];
        }
        __syncthreads();
    }

    #pragma unroll
    for (int i = 0; i < 8; i++) {
        const int m = m0 + tm + i;
        #pragma unroll
        for (int j = 0; j < 4; j++) {
            const int n = n0 + tn + j;
            if (n < N) {
                float v = acc[i][j] + bias[n];
                if (RELU) v = fmaxf(v, 0.f);
                if constexpr (std::is_same_v<OT, __hip_bfloat16>)
                    C[(size_t)m * ldC + n] = __float2bfloat16(v);
                else
                    C[(size_t)m * ldC + n] = v;
            }
        }
    }
}

// ---------------- persistent LSTM scan (one layer, both directions) ----------------
// R0 protocol verbatim; f16 weights from global (R6); weights prefetched into
// registers BEFORE the poll -- 24 x float4 (96 VGPR), pinned component-wise so
// the compiler cannot sink them past the poll/barrier. Their L2 latency hides
// under the exchange RTT; post-barrier compute is pure VALU.
__global__ __launch_bounds__(NTHR) void lstm_scan(
    const __hip_bfloat16* __restrict__ gatesF, const __hip_bfloat16* __restrict__ gatesB,
    const __half* __restrict__ wh16,           // [2 dirs][1536][384] f16
    float* __restrict__ out, unsigned long long* hx_all, int epoch)
{
    __shared__ float hl[2][HID];

    const int blk = blockIdx.x;
    const int g   = blk & 31;          // group (members share blk%8 -> likely same XCD; perf hint only)
    const int m   = blk >> 5;          // member 0..7
    const int dir = g >> 4;
    const int b   = g & 15;
    const int u0  = m * UPB;

    const __hip_bfloat16* gates = dir ? gatesB : gatesF;
    const __half* wh = wh16 + (size_t)dir * 589824;
    unsigned long long* hx = hx_all + g * (2 * HID);   // [2 slots][384] packed

    const int tid = threadIdx.x;
    const int rr  = tid >> 3;          // local unit 0..47
    const int ss  = tid & 7;           // k-part 0..7
    const int ug  = u0 + rr;
    const bool owner = (ss == 0);

    float c_state = 0.f;
    const unsigned tbase = (unsigned)epoch * 2048u;

    for (int t = 0; t < S_LEN; t++) {
        const int tt = dir ? (S_LEN - 1 - t) : t;

        // ---- issue gate-preact loads early (independent of the poll) ----
        float gx0 = 0.f, gx1 = 0.f, gx2 = 0.f, gx3 = 0.f;
        if (owner) {
            const __hip_bfloat16* gp = gates + ((size_t)(b * S_LEN + tt)) * (4 * HID) + ug;
            gx0 = __bfloat162float(gp[0]);
            gx1 = __bfloat162float(gp[HID]);
            gx2 = __bfloat162float(gp[2 * HID]);
            gx3 = __bfloat162float(gp[3 * HID]);
        }

        // ---- prefetch this step's 24 weight float4s BEFORE the poll ----
        float4 wpre[24];
        #pragma unroll
        for (int jj = 0; jj < 6; jj++)
            #pragma unroll
            for (int gt = 0; gt < 4; gt++)
                wpre[jj * 4 + gt] = *(const float4*)(
                    wh + ((size_t)(gt * HID + ug)) * HID + ss * 8 + 64 * jj);
        // pin component-wise (scalar "+v" only; float4 operands are rejected
        // by the backend: "tied indirect register inputs")
        #pragma unroll
        for (int i = 0; i < 24; i++)
            asm volatile("" : "+v"(wpre[i].x), "+v"(wpre[i].y),
                              "+v"(wpre[i].z), "+v"(wpre[i].w));

        // ---- stage h_{t-1} into hl[t&1]: poll packed {tag,val} ----
        if (t == 0) {
            if (tid < 128) {
                hl[0][tid] = 0.f; hl[0][tid + 128] = 0.f; hl[0][tid + 256] = 0.f;
            }
        } else if (tid < 128) {
            const unsigned long long* src = hx + ((t + 1) & 1) * HID;
            float* dst = hl[t & 1];
            const unsigned tgt = tbase + (unsigned)t;
            int pend = 7;
            long guard = 0;
            do {
                if (pend & 1) {
                    const unsigned long long q = __hip_atomic_load(src + tid,
                        __ATOMIC_RELAXED, __HIP_MEMORY_SCOPE_AGENT);
                    if ((unsigned)(q >> 32) >= tgt) {
                        dst[tid] = __uint_as_float((unsigned)q); pend &= ~1;
                    }
                }
                if (pend & 2) {
                    const unsigned long long q = __hip_atomic_load(src + tid + 128,
                        __ATOMIC_RELAXED, __HIP_MEMORY_SCOPE_AGENT);
                    if ((unsigned)(q >> 32) >= tgt) {
                        dst[tid + 128] = __uint_as_float((unsigned)q); pend &= ~2;
                    }
                }
                if (pend & 4) {
                    const unsigned long long q = __hip_atomic_load(src + tid + 256,
                        __ATOMIC_RELAXED, __HIP_MEMORY_SCOPE_AGENT);
                    if ((unsigned)(q >> 32) >= tgt) {
                        dst[tid + 256] = __uint_as_float((unsigned)q); pend &= ~4;
                    }
                }
                if (!pend) break;
                __builtin_amdgcn_s_sleep(1);   // backoff: cut IC hot-line congestion
            } while (++guard < (1L << 22));    // hang -> wrong answer, not deadlock
        }
        __syncthreads();   // the ONLY barrier per step (hl is double-buffered)

        // ---- 4 gate dots over 48 taps; w from registers, h from LDS ----
        const float* hsl = hl[t & 1];
        float a0 = 0.f, a1 = 0.f, a2 = 0.f, a3 = 0.f;
        #pragma unroll
        for (int jj = 0; jj < 6; jj++) {
            const float4 h40 = *(const float4*)(hsl + ss * 8 + 64 * jj);
            const float4 h41 = *(const float4*)(hsl + ss * 8 + 64 * jj + 4);
            #pragma unroll
            for (int gt = 0; gt < 4; gt++) {
                const float4 wv = wpre[jj * 4 + gt];
                const __half2 p0 = unpackh2(wv.x), p1 = unpackh2(wv.y),
                              p2 = unpackh2(wv.z), p3 = unpackh2(wv.w);
                float s = __low2float(p0) * h40.x + __high2float(p0) * h40.y
                        + __low2float(p1) * h40.z + __high2float(p1) * h40.w
                        + __low2float(p2) * h41.x + __high2float(p2) * h41.y
                        + __low2float(p3) * h41.z + __high2float(p3) * h41.w;
                if (gt == 0) a0 += s;
                else if (gt == 1) a1 += s;
                else if (gt == 2) a2 += s;
                else a3 += s;
            }
        }
        // reduce over ss (lane bits 0..2)
        a0 += __shfl_xor(a0, 1, 64); a0 += __shfl_xor(a0, 2, 64); a0 += __shfl_xor(a0, 4, 64);
        a1 += __shfl_xor(a1, 1, 64); a1 += __shfl_xor(a1, 2, 64); a1 += __shfl_xor(a1, 4, 64);
        a2 += __shfl_xor(a2, 1, 64); a2 += __shfl_xor(a2, 2, 64); a2 += __shfl_xor(a2, 4, 64);
        a3 += __shfl_xor(a3, 1, 64); a3 += __shfl_xor(a3, 2, 64); a3 += __shfl_xor(a3, 4, 64);

        if (owner) {
            const float ii = sigf(a0 + gx0);
            const float ff = sigf(a1 + gx1);
            const float gg = tanhfast(a2 + gx2);
            const float oo = sigf(a3 + gx3);
            c_state = ff * c_state + ii * gg;
            const float hn = oo * tanhfast(c_state);
            // publish packed {tag, h_t} — single 8B atomic, data IS the flag
            const unsigned long long pk =
                ((unsigned long long)(tbase + (unsigned)t + 1u) << 32) |
                (unsigned long long)__float_as_uint(hn);
            __hip_atomic_store(hx + (t & 1) * HID + ug, pk,
                               __ATOMIC_RELAXED, __HIP_MEMORY_SCOPE_AGENT);
            // plain store for downstream kernels (dispatch-end release covers it)
            out[((size_t)(b * S_LEN + tt)) * (2 * HID) + dir * HID + ug] = hn;
        }
        // no second barrier: pollers of step t+1 write hl[(t+1)&1], disjoint from hl[t&1]
    }
}

// ---------------- windowed attention ----------------
// score_j = (h_i*w3 + w2) . h_j   (s1[i] and attn_b are constant over j -> cancel in softmax)
__global__ __launch_bounds__(256) void attn_win(
    const float* __restrict__ hcat,   // [16][1024][768], h in cols 0..383
    const float* __restrict__ attnW,  // [1152] = w1|w2|w3
    float* __restrict__ ocat,         // same buffer, writes cols 384..767
    const int* __restrict__ wsz_p)
{
    __shared__ float q[HID];
    __shared__ float sc[96];
    __shared__ float p[96];
    const int blk = blockIdx.x;
    const int b = blk >> 10, i = blk & 1023;
    const int W = *wsz_p;
    const int jlo = max(i - W, 0), jhi = min(i + W, S_LEN - 1);
    const int nj = jhi - jlo + 1;
    const int tid = threadIdx.x;
    const float* hrow = hcat + (size_t)b * S_LEN * 768;

    if (tid < 96) {
        const float4 hv = *(const float4*)(hrow + (size_t)i * 768 + tid * 4);
        const float4 w3 = *(const float4*)(attnW + 768 + tid * 4);
        const float4 w2 = *(const float4*)(attnW + 384 + tid * 4);
        float4 r;
        r.x = hv.x*w3.x + w2.x; r.y = hv.y*w3.y + w2.y;
        r.z = hv.z*w3.z + w2.z; r.w = hv.w*w3.w + w2.w;
        *(float4*)(q + tid * 4) = r;
    }
    __syncthreads();

    const int wv = tid >> 6, lane = tid & 63;
    for (int jj = wv; jj < nj; jj += 4) {
        const float* hj = hrow + (size_t)(jlo + jj) * 768;
        float s = 0.f;
        #pragma unroll
        for (int c = 0; c < 6; c++) { const int d = lane + 64*c; s += q[d] * hj[d]; }
        #pragma unroll
        for (int st = 1; st < 64; st <<= 1) s += __shfl_xor(s, st, 64);
        if (lane == 0) sc[jj] = s;
    }
    __syncthreads();

    if (tid < 64) {
        float v1 = (tid < nj) ? sc[tid] : -3e38f;
        float v2 = (64 + tid < nj) ? sc[64 + tid] : -3e38f;
        float m = fmaxf(v1, v2);
        #pragma unroll
        for (int st = 1; st < 64; st <<= 1) m = fmaxf(m, __shfl_xor(m, st, 64));
        float e1 = (tid < nj) ? __expf(v1 - m) : 0.f;
        float e2 = (64 + tid < nj) ? __expf(v2 - m) : 0.f;
        float sum = e1 + e2;
        #pragma unroll
        for (int st = 1; st < 64; st <<= 1) sum += __shfl_xor(sum, st, 64);
        const float inv = 1.f / sum;
        if (tid < nj) p[tid] = e1 * inv;
        if (64 + tid < nj) p[64 + tid] = e2 * inv;
    }
    __syncthreads();

    if (tid < 192) {
        const int d = tid * 2;
        float s0 = 0.f, s1 = 0.f;
        for (int jj = 0; jj < nj; jj++) {
            const float* hj = hrow + (size_t)(jlo + jj) * 768 + d;
            const float pj = p[jj];
            s0 += pj * hj[0]; s1 += pj * hj[1];
        }
        float* o = ocat + (size_t)b * S_LEN * 768 + (size_t)i * 768 + 384 + d;
        o[0] = s0; o[1] = s1;
    }
}

// ---------------- final 96 -> 1 dot ----------------
__global__ __launch_bounds__(256) void final_dot(
    const float* __restrict__ y2, const float* __restrict__ W3,
    const float* __restrict__ b3, float* __restrict__ outp)
{
    __shared__ float w[96];
    const int tid = threadIdx.x;
    if (tid < 96) w[tid] = W3[tid];
    __syncthreads();
    const int r = blockIdx.x * 256 + tid;
    const float* row = y2 + (size_t)r * 96;
    float s = 0.f;
    #pragma unroll
    for (int c = 0; c < 24; c++) {
        const float4 v = ((const float4*)row)[c];
        s += v.x*w[c*4] + v.y*w[c*4+1] + v.z*w[c*4+2] + v.w*w[c*4+3];
    }
    outp[r] = s + b3[0];
}

// ---------------- launcher ----------------
extern "C" void kernel_launch(void* const* d_in, const int* in_sizes, int n_in,
                              void* d_out, int out_size, void* d_ws, size_t ws_size,
                              hipStream_t stream)
{
    const float* x        = (const float*)d_in[0];
    const float* l1_Wih_f = (const float*)d_in[1];
    const float* l1_Whh_f = (const float*)d_in[2];
    const float* l1_b_f   = (const float*)d_in[3];
    const float* l1_Wih_b = (const float*)d_in[4];
    const float* l1_Whh_b = (const float*)d_in[5];
    const float* l1_b_b   = (const float*)d_in[6];
    const float* l2_Wih_f = (const float*)d_in[7];
    const float* l2_Whh_f = (const float*)d_in[8];
    const float* l2_b_f   = (const float*)d_in[9];
    const float* l2_Wih_b = (const float*)d_in[10];
    const float* l2_Whh_b = (const float*)d_in[11];
    const float* l2_b_b   = (const float*)d_in[12];
    const float* fc1_W    = (const float*)d_in[13];
    const float* fc1_b    = (const float*)d_in[14];
    const float* attn_W   = (const float*)d_in[15];
    /* d_in[16] attn_b: cancels in softmax */
    const float* w1       = (const float*)d_in[17];
    const float* b1       = (const float*)d_in[18];
    const float* w2       = (const float*)d_in[19];
    const float* b2       = (const float*)d_in[20];
    const float* w3       = (const float*)d_in[21];
    const float* b3       = (const float*)d_in[22];
    const int*   wsz      = (const int*)d_in[23];

    // workspace layout (bytes), peak ~201.5 MiB
    char* wsb = (char*)d_ws;
    __hip_bfloat16*     gF  = (__hip_bfloat16*)(wsb);             // 16384*1536 bf16 = 50,331,648 B
    __hip_bfloat16*     gB  = (__hip_bfloat16*)(wsb +  50331648); // 50,331,648 B
    float*              seq = (float*)(wsb + 100663296);          // 16384*768 f32 = 50,331,648 B
    float*              hct = (float*)(wsb + 150994944);          // 16384*768 f32 = 50,331,648 B
    unsigned long long* hx  = (unsigned long long*)(wsb + 201326592); // 24,576 u64 = 196,608 B
    // f16 Whh image: lives in the hct region (dead during both scans):
    //   l1: hct not yet written when l1 scan runs; fc1 overwrites it after.
    //   l2: hct fully consumed by the l2 gate GEMMs before prep16(l2) runs.
    __half*             w16 = (__half*)hct;                       // 2*1536*384 f16 = 2,359,296 B
    // head-phase buffers (gF/gB regions dead after scan2):
    float*              Wc  = (float*)(wsb);                      // 256*768 f32 = 786,432 B
    float*              bc  = (float*)(wsb + 786432);             // 256 f32
    float*              y1  = (float*)(wsb +  50331648);          // 16384*256 f32 = 16,777,216 B
    float*              y2  = (float*)(wsb +  50331648 + 16777216); // 16384*96 f32

    const int M = BATCH * S_LEN;   // 16384
    dim3 tb(256);

    // ---- layer 1 ----
    zero_kernel<<<dim3(96), tb, 0, stream>>>(hx);
    prep16<<<dim3(576), tb, 0, stream>>>(l1_Whh_f, l1_Whh_b, w16);
    gemm_f16<0, __hip_bfloat16><<<dim3(M/128, 12), tb, 0, stream>>>(x, DIN, l1_Wih_f, l1_b_f, gF, 1536, DIN);
    gemm_f16<0, __hip_bfloat16><<<dim3(M/128, 12), tb, 0, stream>>>(x, DIN, l1_Wih_b, l1_b_b, gB, 1536, DIN);
    lstm_scan<<<dim3(256), dim3(NTHR), 0, stream>>>(gF, gB, w16, seq, hx, 0);

    // ---- fc1 (MFMA, f32 out) + windowed attention -> h_cat ----
    gemm_f16<0, float><<<dim3(M/128, 3), tb, 0, stream>>>(seq, 768, fc1_W, fc1_b, hct, 768, 768);
    attn_win<<<dim3(M), tb, 0, stream>>>(hct, attn_W, hct, wsz);

    // ---- layer 2 ----  (no re-zero needed: epoch-tagged monotone tags)
    gemm_f16<0, __hip_bfloat16><<<dim3(M/128, 12), tb, 0, stream>>>(hct, 768, l2_Wih_f, l2_b_f, gF, 1536, 768);
    gemm_f16<0, __hip_bfloat16><<<dim3(M/128, 12), tb, 0, stream>>>(hct, 768, l2_Wih_b, l2_b_b, gB, 1536, 768);
    prep16<<<dim3(576), tb, 0, stream>>>(l2_Whh_f, l2_Whh_b, w16);   // hct consumed above
    lstm_scan<<<dim3(256), dim3(NTHR), 0, stream>>>(gF, gB, w16, seq, hx, 1);

    // ---- head: fused (fc1 -> w1) = one GEMM with Wc = w1@fc1_W, bc = w1@fc1_b + b1 ----
    prep_wc<<<dim3(256), tb, 0, stream>>>(fc1_W, fc1_b, w1, b1, Wc, bc);
    gemm_f16<1, float><<<dim3(M/128, 2), tb, 0, stream>>>(seq, 768, Wc, bc, y1, 256, 768);
    gemm_nt<1, float><<<dim3(M/128, 2), tb, 0, stream>>>(y1, 256, w2, b2, y2, 96, M, 96, 256);
    final_dot<<<dim3(M/256), tb, 0, stream>>>(y2, w3, b3, (float*)d_out);
}

// Round 9
// 5757.155 us; speedup vs baseline: 1.2714x; 1.2714x over previous
//
#include <hip/hip_runtime.h>
#include <hip/hip_bf16.h>
#include <hip/hip_fp16.h>
#include <type_traits>

#define S_LEN 1024
#define BATCH 16
#define HID   384
#define DIN   768

// ---------------- LSTM scan configuration (R0 structure) ----------------
// 32 groups = (dir, batch); 8 members per group; UPB units per member.
// R6 scan = session best (2.33us/step). Protocol-floor evidence:
//   R5 (LDS-resident weights)    3.19us/step  -- post-barrier LDS serialization
//   R8 (register prefetch+pin)   3.01us/step  -- vmcnt in-order forces early wait
//   R6 (f16 stream, in-compute)  2.33us/step  -- loads hidden by wave overlap
// Do NOT re-schedule the weight loads; the compiler's placement is optimal here.
#define GRP 8
#define UPB 48
#define NTHR 384

__device__ __forceinline__ float sigf(float x)     { return 1.f/(1.f + __expf(-x)); }
__device__ __forceinline__ float tanhfast(float x) { return 1.f - 2.f/(__expf(2.f*x) + 1.f); }

__device__ __forceinline__ __half2 unpackh2(float f) {
    return __builtin_bit_cast(__half2, f);
}

typedef __attribute__((ext_vector_type(8))) _Float16 f16x8;
typedef __attribute__((ext_vector_type(4))) float f32x4;

// ---------------- zero init: packed h-exchange {tag,val} buffer ----------------
// 32 groups x 2 slots x 384 units x 8B = 196,608 B. Must be zeroed every launch
// (harness poisons d_ws with 0xAA -> tags would read as huge -> stale accept).
__global__ void zero_kernel(unsigned long long* hx)
{
    int i = blockIdx.x * blockDim.x + threadIdx.x;
    if (i < 32*2*HID) hx[i] = 0ull;
}

// ---------------- Whh f32 -> f16 pre-convert (both directions) ----------------
__global__ void prep16(const float* __restrict__ wf, const float* __restrict__ wb,
                       __half* __restrict__ o)
{
    int i = blockIdx.x * 256 + threadIdx.x;   // 0..147455 float4s per matrix
    if (i < 147456) {
        const float4 a = ((const float4*)wf)[i];
        const float4 b = ((const float4*)wb)[i];
        __half2* of = (__half2*)o;
        of[2*i]   = __halves2half2(__float2half(a.x), __float2half(a.y));
        of[2*i+1] = __halves2half2(__float2half(a.z), __float2half(a.w));
        __half2* ob = (__half2*)(o + 589824);
        ob[2*i]   = __halves2half2(__float2half(b.x), __float2half(b.y));
        ob[2*i+1] = __halves2half2(__float2half(b.z), __float2half(b.w));
    }
}

// ---------------- head fusion prep: Wc = w1 @ fc1_W ; bc = w1 @ fc1_b + b1 ----
// Exact algebra: h2 = seq@fc1W^T + fc1b ; y1 = relu(h2@w1^T + b1)
//             -> y1 = relu(seq @ Wc^T + bc), Wc[n][k] = sum_j w1[n][j]*fc1W[j][k].
// Validated in R8 (absmax bit-identical).
__global__ __launch_bounds__(256) void prep_wc(
    const float* __restrict__ fc1W,  // [384][768]
    const float* __restrict__ fc1b,  // [384]
    const float* __restrict__ w1,    // [256][384]
    const float* __restrict__ b1,    // [256]
    float* __restrict__ Wc,          // [256][768]
    float* __restrict__ bc)          // [256]
{
    __shared__ float wr[384];
    const int n = blockIdx.x;
    const int tid = threadIdx.x;
    if (tid < 192) {
        const float2 v = *(const float2*)(w1 + (size_t)n * 384 + tid * 2);
        wr[tid*2] = v.x; wr[tid*2+1] = v.y;
    }
    __syncthreads();
    float s0 = 0.f, s1 = 0.f, s2 = 0.f;
    for (int j = 0; j < 384; j++) {
        const float w = wr[j];
        const float* fr = fc1W + (size_t)j * 768;
        s0 += w * fr[tid]; s1 += w * fr[tid + 256]; s2 += w * fr[tid + 512];
    }
    Wc[(size_t)n*768 + tid]       = s0;
    Wc[(size_t)n*768 + tid + 256] = s1;
    Wc[(size_t)n*768 + tid + 512] = s2;
    if (tid == 0) {
        float s = b1[n];
        for (int j = 0; j < 384; j++) s += wr[j] * fc1b[j];
        bc[n] = s;
    }
}

// ---------------- MFMA f16 GEMM: C = act(A(f32) @ W(f32)^T + bias) ----------------
// M mult 128, N mult 128, K mult 64. BM=BN=128, BK=64, 256 threads = 4 waves 2x2,
// wave-tile 64x64, acc[4][4] f32x4. LDS tiles f16 [128][128B], XOR swizzle
// byte ^= (row&7)<<4 on write and read -> conflict-free. Validated R6/R8.
template<int RELU, typename OT>
__global__ __launch_bounds__(256) void gemm_f16(
    const float* __restrict__ A, int ldA,
    const float* __restrict__ W,            // [N][K] f32
    const float* __restrict__ bias,
    OT* __restrict__ C, int ldC,
    int K)
{
    __shared__ char Al[128 * 128];
    __shared__ char Bl[128 * 128];
    const int tid  = threadIdx.x;
    const int m0   = blockIdx.x * 128;
    const int n0   = blockIdx.y * 128;
    const int wid  = tid >> 6, lane = tid & 63;
    const int wm   = (wid >> 1) * 64, wn = (wid & 1) * 64;
    const int fr   = lane & 15, fq = lane >> 4;

    f32x4 acc[4][4] = {};

    const int srow = tid >> 1;            // 0..127
    const int sseg = (tid & 1) * 32;      // element offset 0 or 32

    for (int k0 = 0; k0 < K; k0 += 64) {
        {
            const float* ap = A + (size_t)(m0 + srow) * ldA + k0 + sseg;
            const float* wp = W + (size_t)(n0 + srow) * K   + k0 + sseg;
            _Float16 ta[32], tw[32];
            #pragma unroll
            for (int q = 0; q < 8; q++) {
                const float4 va = *(const float4*)(ap + q * 4);
                const float4 vw = *(const float4*)(wp + q * 4);
                ta[4*q+0] = (_Float16)va.x; ta[4*q+1] = (_Float16)va.y;
                ta[4*q+2] = (_Float16)va.z; ta[4*q+3] = (_Float16)va.w;
                tw[4*q+0] = (_Float16)vw.x; tw[4*q+1] = (_Float16)vw.y;
                tw[4*q+2] = (_Float16)vw.z; tw[4*q+3] = (_Float16)vw.w;
            }
            const int xr = (srow & 7) << 4;
            #pragma unroll
            for (int c = 0; c < 4; c++) {
                const int col = (sseg * 2 + c * 16) ^ xr;   // byte col
                *(f16x8*)(Al + srow * 128 + col) = *(f16x8*)&ta[c * 8];
                *(f16x8*)(Bl + srow * 128 + col) = *(f16x8*)&tw[c * 8];
            }
        }
        __syncthreads();

        #pragma unroll
        for (int kc = 0; kc < 2; kc++) {
            f16x8 af[4], bf[4];
            #pragma unroll
            for (int mt = 0; mt < 4; mt++) {
                const int r = wm + mt * 16 + fr;
                af[mt] = *(const f16x8*)(Al + r * 128 + ((kc * 64 + fq * 16) ^ ((r & 7) << 4)));
            }
            #pragma unroll
            for (int nt = 0; nt < 4; nt++) {
                const int r = wn + nt * 16 + fr;
                bf[nt] = *(const f16x8*)(Bl + r * 128 + ((kc * 64 + fq * 16) ^ ((r & 7) << 4)));
            }
            #pragma unroll
            for (int mt = 0; mt < 4; mt++)
                #pragma unroll
                for (int nt = 0; nt < 4; nt++)
                    acc[mt][nt] = __builtin_amdgcn_mfma_f32_16x16x32_f16(
                        af[mt], bf[nt], acc[mt][nt], 0, 0, 0);
        }
        __syncthreads();
    }

    #pragma unroll
    for (int mt = 0; mt < 4; mt++) {
        #pragma unroll
        for (int nt = 0; nt < 4; nt++) {
            const int n = n0 + wn + nt * 16 + fr;
            const float bv = bias[n];
            #pragma unroll
            for (int j = 0; j < 4; j++) {
                const int m = m0 + wm + mt * 16 + fq * 4 + j;
                float v = acc[mt][nt][j] + bv;
                if (RELU) v = fmaxf(v, 0.f);
                if constexpr (std::is_same_v<OT, __hip_bfloat16>)
                    C[(size_t)m * ldC + n] = __float2bfloat16(v);
                else
                    C[(size_t)m * ldC + n] = v;
            }
        }
    }
}

// ---------------- generic fp32 GEMM (kept for small/odd-N tails) ----------------
template<int RELU, typename OT>
__global__ __launch_bounds__(256) void gemm_nt(
    const float* __restrict__ A, int ldA,
    const float* __restrict__ W,
    const float* __restrict__ bias,
    OT* __restrict__ C, int ldC,
    int M, int N, int K)
{
    __shared__ float As[16][132];
    __shared__ float Ws[16][68];
    const int tid = threadIdx.x;
    const int m0 = blockIdx.x * 128;
    const int n0 = blockIdx.y * 64;
    const int tm = (tid & 15) * 8;
    const int tn = (tid >> 4) * 4;

    float acc[8][4];
    #pragma unroll
    for (int i = 0; i < 8; i++)
        #pragma unroll
        for (int j = 0; j < 4; j++) acc[i][j] = 0.f;

    const int lrow = tid >> 2;          // 0..63
    const int lk   = (tid & 3) * 4;     // 0,4,8,12

    for (int k0 = 0; k0 < K; k0 += 16) {
        #pragma unroll
        for (int p = 0; p < 2; p++) {
            const int r = lrow + p * 64;
            const float4 av = *(const float4*)(A + (size_t)(m0 + r) * ldA + k0 + lk);
            As[lk+0][r] = av.x; As[lk+1][r] = av.y; As[lk+2][r] = av.z; As[lk+3][r] = av.w;
        }
        {
            float4 wv = make_float4(0.f, 0.f, 0.f, 0.f);
            if (n0 + lrow < N) wv = *(const float4*)(W + (size_t)(n0 + lrow) * K + k0 + lk);
            Ws[lk+0][lrow] = wv.x; Ws[lk+1][lrow] = wv.y; Ws[lk+2][lrow] = wv.z; Ws[lk+3][lrow] = wv.w;
        }
        __syncthreads();
        #pragma unroll
        for (int k = 0; k < 16; k++) {
            const float4 a0 = *(const float4*)&As[k][tm];
            const float4 a1 = *(const float4*)&As[k][tm + 4];
            const float4 bv = *(const float4*)&Ws[k][tn];
            const float am[8] = {a0.x, a0.y, a0.z, a0.w, a1.x, a1.y, a1.z, a1.w};
            const float bb[4] = {bv.x, bv.y, bv.z, bv.w};
            #pragma unroll
            for (int i = 0; i < 8; i++)
                #pragma unroll
                for (int j = 0; j < 4; j++) acc[i][j] += am[i] * bb[j];
        }
        __syncthreads();
    }

    #pragma unroll
    for (int i = 0; i < 8; i++) {
        const int m = m0 + tm + i;
        #pragma unroll
        for (int j = 0; j < 4; j++) {
            const int n = n0 + tn + j;
            if (n < N) {
                float v = acc[i][j] + bias[n];
                if (RELU) v = fmaxf(v, 0.f);
                if constexpr (std::is_same_v<OT, __hip_bfloat16>)
                    C[(size_t)m * ldC + n] = __float2bfloat16(v);
                else
                    C[(size_t)m * ldC + n] = v;
            }
        }
    }
}

// ---------------- persistent LSTM scan (one layer, both directions) ----------------
// R6 version VERBATIM (session-best scan). R0 protocol; f16 weights streamed
// from global INSIDE the post-barrier compute (compiler-scheduled; measured
// faster than LDS-resident [R5] and register-prefetch [R8] alternatives).
// Taps: thread (rr=tid>>3, ss=tid&7): unit rr, k = ss*8 + 64*jj + e (jj<6,e<8).
// h exchange: packed 8B {tag(hi32), val(lo32)} agent-scope atomics; data IS the
// flag. Pollers tid<128, 3 packets each, per-element ready mask + s_sleep
// backoff. hl double-buffered -> ONE barrier per step. 2-slot rotation:
// publish(step s) -> slot s&1 tag s+1; stage(step s) polls slot (s-1)&1 >= s.
__global__ __launch_bounds__(NTHR) void lstm_scan(
    const __hip_bfloat16* __restrict__ gatesF, const __hip_bfloat16* __restrict__ gatesB,
    const __half* __restrict__ wh16,           // [2 dirs][1536][384] f16
    float* __restrict__ out, unsigned long long* hx_all, int epoch)
{
    __shared__ float hl[2][HID];

    const int blk = blockIdx.x;
    const int g   = blk & 31;          // group (members share blk%8 -> likely same XCD; perf hint only)
    const int m   = blk >> 5;          // member 0..7
    const int dir = g >> 4;
    const int b   = g & 15;
    const int u0  = m * UPB;

    const __hip_bfloat16* gates = dir ? gatesB : gatesF;
    const __half* wh = wh16 + (size_t)dir * 589824;
    unsigned long long* hx = hx_all + g * (2 * HID);   // [2 slots][384] packed

    const int tid = threadIdx.x;
    const int rr  = tid >> 3;          // local unit 0..47
    const int ss  = tid & 7;           // k-part 0..7
    const int ug  = u0 + rr;
    const bool owner = (ss == 0);

    float c_state = 0.f;
    const unsigned tbase = (unsigned)epoch * 2048u;

    for (int t = 0; t < S_LEN; t++) {
        const int tt = dir ? (S_LEN - 1 - t) : t;

        // issue this step's gate-preact loads early (independent of the poll)
        float gx0 = 0.f, gx1 = 0.f, gx2 = 0.f, gx3 = 0.f;
        if (owner) {
            const __hip_bfloat16* gp = gates + ((size_t)(b * S_LEN + tt)) * (4 * HID) + ug;
            gx0 = __bfloat162float(gp[0]);
            gx1 = __bfloat162float(gp[HID]);
            gx2 = __bfloat162float(gp[2 * HID]);
            gx3 = __bfloat162float(gp[3 * HID]);
        }

        // stage h_{t-1} into hl[t&1]: poll packed {tag,val}, per-element ready mask
        if (t == 0) {
            if (tid < 128) {
                hl[0][tid] = 0.f; hl[0][tid + 128] = 0.f; hl[0][tid + 256] = 0.f;
            }
        } else if (tid < 128) {
            const unsigned long long* src = hx + ((t + 1) & 1) * HID;
            float* dst = hl[t & 1];
            const unsigned tgt = tbase + (unsigned)t;
            int pend = 7;
            long guard = 0;
            do {
                if (pend & 1) {
                    const unsigned long long q = __hip_atomic_load(src + tid,
                        __ATOMIC_RELAXED, __HIP_MEMORY_SCOPE_AGENT);
                    if ((unsigned)(q >> 32) >= tgt) {
                        dst[tid] = __uint_as_float((unsigned)q); pend &= ~1;
                    }
                }
                if (pend & 2) {
                    const unsigned long long q = __hip_atomic_load(src + tid + 128,
                        __ATOMIC_RELAXED, __HIP_MEMORY_SCOPE_AGENT);
                    if ((unsigned)(q >> 32) >= tgt) {
                        dst[tid + 128] = __uint_as_float((unsigned)q); pend &= ~2;
                    }
                }
                if (pend & 4) {
                    const unsigned long long q = __hip_atomic_load(src + tid + 256,
                        __ATOMIC_RELAXED, __HIP_MEMORY_SCOPE_AGENT);
                    if ((unsigned)(q >> 32) >= tgt) {
                        dst[tid + 256] = __uint_as_float((unsigned)q); pend &= ~4;
                    }
                }
                if (!pend) break;
                __builtin_amdgcn_s_sleep(1);   // backoff: cut IC hot-line congestion
            } while (++guard < (1L << 22));    // hang -> wrong answer, not deadlock
        }
        __syncthreads();   // the ONLY barrier per step (hl is double-buffered)

        // 4 gate dots over this thread's 48 taps; w streamed f16 from global,
        // h from LDS (8 distinct 16B lines/wave -> broadcast, conflict-free)
        const float* hsl = hl[t & 1];
        float a0 = 0.f, a1 = 0.f, a2 = 0.f, a3 = 0.f;
        #pragma unroll
        for (int jj = 0; jj < 6; jj++) {
            const float4 h40 = *(const float4*)(hsl + ss * 8 + 64 * jj);
            const float4 h41 = *(const float4*)(hsl + ss * 8 + 64 * jj + 4);
            #pragma unroll
            for (int gt = 0; gt < 4; gt++) {
                const float4 wv = *(const float4*)(wh + ((size_t)(gt * HID + ug)) * HID + ss * 8 + 64 * jj);
                const __half2 p0 = unpackh2(wv.x), p1 = unpackh2(wv.y),
                              p2 = unpackh2(wv.z), p3 = unpackh2(wv.w);
                float s = __low2float(p0) * h40.x + __high2float(p0) * h40.y
                        + __low2float(p1) * h40.z + __high2float(p1) * h40.w
                        + __low2float(p2) * h41.x + __high2float(p2) * h41.y
                        + __low2float(p3) * h41.z + __high2float(p3) * h41.w;
                if (gt == 0) a0 += s;
                else if (gt == 1) a1 += s;
                else if (gt == 2) a2 += s;
                else a3 += s;
            }
        }
        // reduce over ss (lane bits 0..2)
        a0 += __shfl_xor(a0, 1, 64); a0 += __shfl_xor(a0, 2, 64); a0 += __shfl_xor(a0, 4, 64);
        a1 += __shfl_xor(a1, 1, 64); a1 += __shfl_xor(a1, 2, 64); a1 += __shfl_xor(a1, 4, 64);
        a2 += __shfl_xor(a2, 1, 64); a2 += __shfl_xor(a2, 2, 64); a2 += __shfl_xor(a2, 4, 64);
        a3 += __shfl_xor(a3, 1, 64); a3 += __shfl_xor(a3, 2, 64); a3 += __shfl_xor(a3, 4, 64);

        if (owner) {
            const float ii = sigf(a0 + gx0);
            const float ff = sigf(a1 + gx1);
            const float gg = tanhfast(a2 + gx2);
            const float oo = sigf(a3 + gx3);
            c_state = ff * c_state + ii * gg;
            const float hn = oo * tanhfast(c_state);
            // publish packed {tag, h_t} — single 8B atomic, data IS the flag
            const unsigned long long pk =
                ((unsigned long long)(tbase + (unsigned)t + 1u) << 32) |
                (unsigned long long)__float_as_uint(hn);
            __hip_atomic_store(hx + (t & 1) * HID + ug, pk,
                               __ATOMIC_RELAXED, __HIP_MEMORY_SCOPE_AGENT);
            // plain store for downstream kernels (dispatch-end release covers it)
            out[((size_t)(b * S_LEN + tt)) * (2 * HID) + dir * HID + ug] = hn;
        }
        // no second barrier: pollers of step t+1 write hl[(t+1)&1], disjoint from hl[t&1]
    }
}

// ---------------- windowed attention ----------------
// score_j = (h_i*w3 + w2) . h_j   (s1[i] and attn_b are constant over j -> cancel in softmax)
__global__ __launch_bounds__(256) void attn_win(
    const float* __restrict__ hcat,   // [16][1024][768], h in cols 0..383
    const float* __restrict__ attnW,  // [1152] = w1|w2|w3
    float* __restrict__ ocat,         // same buffer, writes cols 384..767
    const int* __restrict__ wsz_p)
{
    __shared__ float q[HID];
    __shared__ float sc[96];
    __shared__ float p[96];
    const int blk = blockIdx.x;
    const int b = blk >> 10, i = blk & 1023;
    const int W = *wsz_p;
    const int jlo = max(i - W, 0), jhi = min(i + W, S_LEN - 1);
    const int nj = jhi - jlo + 1;
    const int tid = threadIdx.x;
    const float* hrow = hcat + (size_t)b * S_LEN * 768;

    if (tid < 96) {
        const float4 hv = *(const float4*)(hrow + (size_t)i * 768 + tid * 4);
        const float4 w3 = *(const float4*)(attnW + 768 + tid * 4);
        const float4 w2 = *(const float4*)(attnW + 384 + tid * 4);
        float4 r;
        r.x = hv.x*w3.x + w2.x; r.y = hv.y*w3.y + w2.y;
        r.z = hv.z*w3.z + w2.z; r.w = hv.w*w3.w + w2.w;
        *(float4*)(q + tid * 4) = r;
    }
    __syncthreads();

    const int wv = tid >> 6, lane = tid & 63;
    for (int jj = wv; jj < nj; jj += 4) {
        const float* hj = hrow + (size_t)(jlo + jj) * 768;
        float s = 0.f;
        #pragma unroll
        for (int c = 0; c < 6; c++) { const int d = lane + 64*c; s += q[d] * hj[d]; }
        #pragma unroll
        for (int st = 1; st < 64; st <<= 1) s += __shfl_xor(s, st, 64);
        if (lane == 0) sc[jj] = s;
    }
    __syncthreads();

    if (tid < 64) {
        float v1 = (tid < nj) ? sc[tid] : -3e38f;
        float v2 = (64 + tid < nj) ? sc[64 + tid] : -3e38f;
        float m = fmaxf(v1, v2);
        #pragma unroll
        for (int st = 1; st < 64; st <<= 1) m = fmaxf(m, __shfl_xor(m, st, 64));
        float e1 = (tid < nj) ? __expf(v1 - m) : 0.f;
        float e2 = (64 + tid < nj) ? __expf(v2 - m) : 0.f;
        float sum = e1 + e2;
        #pragma unroll
        for (int st = 1; st < 64; st <<= 1) sum += __shfl_xor(sum, st, 64);
        const float inv = 1.f / sum;
        if (tid < nj) p[tid] = e1 * inv;
        if (64 + tid < nj) p[64 + tid] = e2 * inv;
    }
    __syncthreads();

    if (tid < 192) {
        const int d = tid * 2;
        float s0 = 0.f, s1 = 0.f;
        for (int jj = 0; jj < nj; jj++) {
            const float* hj = hrow + (size_t)(jlo + jj) * 768 + d;
            const float pj = p[jj];
            s0 += pj * hj[0]; s1 += pj * hj[1];
        }
        float* o = ocat + (size_t)b * S_LEN * 768 + (size_t)i * 768 + 384 + d;
        o[0] = s0; o[1] = s1;
    }
}

// ---------------- final 96 -> 1 dot ----------------
__global__ __launch_bounds__(256) void final_dot(
    const float* __restrict__ y2, const float* __restrict__ W3,
    const float* __restrict__ b3, float* __restrict__ outp)
{
    __shared__ float w[96];
    const int tid = threadIdx.x;
    if (tid < 96) w[tid] = W3[tid];
    __syncthreads();
    const int r = blockIdx.x * 256 + tid;
    const float* row = y2 + (size_t)r * 96;
    float s = 0.f;
    #pragma unroll
    for (int c = 0; c < 24; c++) {
        const float4 v = ((const float4*)row)[c];
        s += v.x*w[c*4] + v.y*w[c*4+1] + v.z*w[c*4+2] + v.w*w[c*4+3];
    }
    outp[r] = s + b3[0];
}

// ---------------- launcher ----------------
extern "C" void kernel_launch(void* const* d_in, const int* in_sizes, int n_in,
                              void* d_out, int out_size, void* d_ws, size_t ws_size,
                              hipStream_t stream)
{
    const float* x        = (const float*)d_in[0];
    const float* l1_Wih_f = (const float*)d_in[1];
    const float* l1_Whh_f = (const float*)d_in[2];
    const float* l1_b_f   = (const float*)d_in[3];
    const float* l1_Wih_b = (const float*)d_in[4];
    const float* l1_Whh_b = (const float*)d_in[5];
    const float* l1_b_b   = (const float*)d_in[6];
    const float* l2_Wih_f = (const float*)d_in[7];
    const float* l2_Whh_f = (const float*)d_in[8];
    const float* l2_b_f   = (const float*)d_in[9];
    const float* l2_Wih_b = (const float*)d_in[10];
    const float* l2_Whh_b = (const float*)d_in[11];
    const float* l2_b_b   = (const float*)d_in[12];
    const float* fc1_W    = (const float*)d_in[13];
    const float* fc1_b    = (const float*)d_in[14];
    const float* attn_W   = (const float*)d_in[15];
    /* d_in[16] attn_b: cancels in softmax */
    const float* w1       = (const float*)d_in[17];
    const float* b1       = (const float*)d_in[18];
    const float* w2       = (const float*)d_in[19];
    const float* b2       = (const float*)d_in[20];
    const float* w3       = (const float*)d_in[21];
    const float* b3       = (const float*)d_in[22];
    const int*   wsz      = (const int*)d_in[23];

    // workspace layout (bytes), peak ~201.5 MiB
    char* wsb = (char*)d_ws;
    __hip_bfloat16*     gF  = (__hip_bfloat16*)(wsb);             // 16384*1536 bf16 = 50,331,648 B
    __hip_bfloat16*     gB  = (__hip_bfloat16*)(wsb +  50331648); // 50,331,648 B
    float*              seq = (float*)(wsb + 100663296);          // 16384*768 f32 = 50,331,648 B
    float*              hct = (float*)(wsb + 150994944);          // 16384*768 f32 = 50,331,648 B
    unsigned long long* hx  = (unsigned long long*)(wsb + 201326592); // 24,576 u64 = 196,608 B
    // f16 Whh image: lives in the hct region (dead during both scans):
    //   l1: hct not yet written when l1 scan runs; fc1 overwrites it after.
    //   l2: hct fully consumed by the l2 gate GEMMs before prep16(l2) runs.
    __half*             w16 = (__half*)hct;                       // 2*1536*384 f16 = 2,359,296 B
    // head-phase buffers (gF/gB regions dead after scan2):
    float*              Wc  = (float*)(wsb);                      // 256*768 f32 = 786,432 B
    float*              bc  = (float*)(wsb + 786432);             // 256 f32
    float*              y1  = (float*)(wsb +  50331648);          // 16384*256 f32 = 16,777,216 B
    float*              y2  = (float*)(wsb +  50331648 + 16777216); // 16384*96 f32

    const int M = BATCH * S_LEN;   // 16384
    dim3 tb(256);

    // ---- layer 1 ----
    zero_kernel<<<dim3(96), tb, 0, stream>>>(hx);
    prep16<<<dim3(576), tb, 0, stream>>>(l1_Whh_f, l1_Whh_b, w16);
    gemm_f16<0, __hip_bfloat16><<<dim3(M/128, 12), tb, 0, stream>>>(x, DIN, l1_Wih_f, l1_b_f, gF, 1536, DIN);
    gemm_f16<0, __hip_bfloat16><<<dim3(M/128, 12), tb, 0, stream>>>(x, DIN, l1_Wih_b, l1_b_b, gB, 1536, DIN);
    lstm_scan<<<dim3(256), dim3(NTHR), 0, stream>>>(gF, gB, w16, seq, hx, 0);

    // ---- fc1 (MFMA, f32 out) + windowed attention -> h_cat ----
    gemm_f16<0, float><<<dim3(M/128, 3), tb, 0, stream>>>(seq, 768, fc1_W, fc1_b, hct, 768, 768);
    attn_win<<<dim3(M), tb, 0, stream>>>(hct, attn_W, hct, wsz);

    // ---- layer 2 ----  (no re-zero needed: epoch-tagged monotone tags)
    gemm_f16<0, __hip_bfloat16><<<dim3(M/128, 12), tb, 0, stream>>>(hct, 768, l2_Wih_f, l2_b_f, gF, 1536, 768);
    gemm_f16<0, __hip_bfloat16><<<dim3(M/128, 12), tb, 0, stream>>>(hct, 768, l2_Wih_b, l2_b_b, gB, 1536, 768);
    prep16<<<dim3(576), tb, 0, stream>>>(l2_Whh_f, l2_Whh_b, w16);   // hct consumed above
    lstm_scan<<<dim3(256), dim3(NTHR), 0, stream>>>(gF, gB, w16, seq, hx, 1);

    // ---- head: fused (fc1 -> w1) = one GEMM with Wc = w1@fc1_W, bc = w1@fc1_b + b1 ----
    prep_wc<<<dim3(256), tb, 0, stream>>>(fc1_W, fc1_b, w1, b1, Wc, bc);
    gemm_f16<1, float><<<dim3(M/128, 2), tb, 0, stream>>>(seq, 768, Wc, bc, y1, 256, 768);
    gemm_nt<1, float><<<dim3(M/128, 2), tb, 0, stream>>>(y1, 256, w2, b2, y2, 96, M, 96, 256);
    final_dot<<<dim3(M/256), tb, 0, stream>>>(y2, w3, b3, (float*)d_out);
}